// Round 1
// baseline (388.256 us; speedup 1.0000x reference)
//
#include <hip/hip_runtime.h>

#define NB 16
#define NC 256
#define NS 64
#define NL 4096

// Kernel 1: per-(c,s) parameter precompute.
// ws layout: float4[c*NS+s] = { wr, wi, 2*br, 2*bi }
//   w   = exp(a*dt),  b = c * (exp(a*dt)-1)/a
__global__ __launch_bounds__(256) void s4d_params(const float* __restrict__ log_dt,
                                                  const float* __restrict__ a_real,
                                                  const float* __restrict__ a_imag,
                                                  const float* __restrict__ cv,
                                                  float4* __restrict__ out) {
    int i = blockIdx.x * 256 + threadIdx.x;
    if (i >= NC * NS) return;
    int c = i >> 6;
    float dt = expf(log_dt[c]);
    float ar = -expf(a_real[i]);
    float ai = a_imag[i];
    float adr = ar * dt, adi = ai * dt;
    float e = expf(adr);
    float sn, cs;
    sincosf(adi, &sn, &cs);
    float wr = e * cs, wi = e * sn;          // w = exp(a*dt)
    // (w - 1) / a  =  (w-1) * conj(a) / |a|^2
    float inv = 1.0f / (ar * ar + ai * ai);
    float numr = wr - 1.0f, numi = wi;
    float qr = (numr * ar + numi * ai) * inv;
    float qi = (numi * ar - numr * ai) * inv;
    float c0 = cv[2 * i], c1 = cv[2 * i + 1];
    float br = c0 * qr - c1 * qi;
    float bi = c0 * qi + c1 * qr;
    out[i] = make_float4(wr, wi, 2.0f * br, 2.0f * bi);
}

// Kernel 2: recurrent scan. One 64-lane wave per (b,c); lane = state s.
// h_s[n] = w_s h_s[n-1] + x[n];  y[n] = sum_s (2br*hr - 2bi*hi)
__global__ __launch_bounds__(64) void s4d_scan(const float* __restrict__ x,
                                               const float4* __restrict__ params,
                                               float* __restrict__ y) {
    const int bc = blockIdx.x;          // b*NC + c
    const int c = bc & (NC - 1);
    const int lane = threadIdx.x;       // state index s
    const float4 p = params[c * NS + lane];
    const float wr = p.x, wi = p.y, br = p.z, bi = p.w;
    const float* xp = x + (size_t)bc * NL;
    float* yp = y + (size_t)bc * NL;

    __shared__ float xs[64];
    __shared__ float rs[64][65];        // [t][s], stride 65 -> conflict-free both ways

    float hr = 0.0f, hi = 0.0f;

    for (int l0 = 0; l0 < NL; l0 += 64) {
        xs[lane] = xp[l0 + lane];       // coalesced tile load
        __syncthreads();
#pragma unroll
        for (int t = 0; t < 64; ++t) {
            float xv = xs[t];                               // LDS broadcast
            float t1 = __builtin_fmaf(-wi, hi, xv);
            float nhr = __builtin_fmaf(wr, hr, t1);         // hr' = wr*hr - wi*hi + x
            hi = __builtin_fmaf(wr, hi, wi * hr);           // hi' = wr*hi + wi*hr (old hr)
            hr = nhr;
            rs[t][lane] = __builtin_fmaf(br, hr, -bi * hi); // 2*Re(b*h) contribution
        }
        __syncthreads();
        // lane t sums over states: y[l0+t] = sum_s rs[t][s]
        float a0 = 0.f, a1 = 0.f, a2 = 0.f, a3 = 0.f;
#pragma unroll
        for (int k = 0; k < 64; k += 4) {
            a0 += rs[lane][k + 0];
            a1 += rs[lane][k + 1];
            a2 += rs[lane][k + 2];
            a3 += rs[lane][k + 3];
        }
        yp[l0 + lane] = (a0 + a1) + (a2 + a3);   // coalesced store
        __syncthreads();                         // rs reuse hazard for next tile
    }
}

extern "C" void kernel_launch(void* const* d_in, const int* in_sizes, int n_in,
                              void* d_out, int out_size, void* d_ws, size_t ws_size,
                              hipStream_t stream) {
    const float* x      = (const float*)d_in[0];
    const float* log_dt = (const float*)d_in[1];
    const float* a_real = (const float*)d_in[2];
    const float* a_imag = (const float*)d_in[3];
    const float* cv     = (const float*)d_in[4];
    float* y = (float*)d_out;
    float4* params = (float4*)d_ws;   // NC*NS*16 B = 256 KiB, recomputed every call

    hipLaunchKernelGGL(s4d_params, dim3((NC * NS + 255) / 256), dim3(256), 0, stream,
                       log_dt, a_real, a_imag, cv, params);
    hipLaunchKernelGGL(s4d_scan, dim3(NB * NC), dim3(64), 0, stream,
                       x, params, y);
}

// Round 2
// 320.830 us; speedup vs baseline: 1.2102x; 1.2102x over previous
//
#include <hip/hip_runtime.h>

typedef float v2f __attribute__((ext_vector_type(2)));

#define NB 16
#define NC 256
#define NS 64
#define NL 4096

// Kernel 1: per-(c,s) parameter precompute.
// ws layout: float4[c*NS+s] = { wr, wi, 2*br, 2*bi }
__global__ __launch_bounds__(256) void s4d_params(const float* __restrict__ log_dt,
                                                  const float* __restrict__ a_real,
                                                  const float* __restrict__ a_imag,
                                                  const float* __restrict__ cv,
                                                  float4* __restrict__ out) {
    int i = blockIdx.x * 256 + threadIdx.x;
    if (i >= NC * NS) return;
    int c = i >> 6;
    float dt = expf(log_dt[c]);
    float ar = -expf(a_real[i]);
    float ai = a_imag[i];
    float adr = ar * dt, adi = ai * dt;
    float e = expf(adr);
    float sn, cs;
    sincosf(adi, &sn, &cs);
    float wr = e * cs, wi = e * sn;          // w = exp(a*dt)
    float inv = 1.0f / (ar * ar + ai * ai);
    float numr = wr - 1.0f, numi = wi;
    float qr = (numr * ar + numi * ai) * inv;
    float qi = (numi * ar - numr * ai) * inv;
    float c0 = cv[2 * i], c1 = cv[2 * i + 1];
    float br = c0 * qr - c1 * qi;
    float bi = c0 * qi + c1 * qr;
    out[i] = make_float4(wr, wi, 2.0f * br, 2.0f * bi);
}

// Kernel 2: recurrent scan. One 64-lane wave per (b,c); lane = state s.
// State g = 2*b*h folded:  g[n] = w*g[n-1] + (2b)*x[n];  y[n] = sum_s Re(g_s[n])
__global__ __launch_bounds__(64, 4) void s4d_scan(const float* __restrict__ x,
                                                  const float4* __restrict__ params,
                                                  float* __restrict__ y) {
    const int bc = blockIdx.x;          // b*NC + c
    const int c = bc & (NC - 1);
    const int lane = threadIdx.x;       // state index s
    const float4 p = params[c * NS + lane];
    const v2f w1 = {p.x, p.y};          // (wr,  wi)
    const v2f w2 = {-p.y, p.x};         // (-wi, wr)
    const v2f b2 = {p.z, p.w};          // (2br, 2bi)
    const float* xp = x + (size_t)bc * NL;
    float* yp = y + (size_t)bc * NL;

    __shared__ float xs[64];
    __shared__ float rs[32][65];        // [t][s], stride 65 -> conflict-free both ways

    v2f g = {0.0f, 0.0f};
    float xnext = xp[lane];             // prefetch tile 0

    for (int tile = 0; tile < 64; ++tile) {
        xs[lane] = xnext;               // previous tile's readers done (barrier below)
        __syncthreads();
        if (tile < 63) xnext = xp[(tile + 1) * 64 + lane];  // prefetch next tile

        for (int sub = 0; sub < 2; ++sub) {
            const int base = sub * 32;
#pragma unroll
            for (int t = 0; t < 32; ++t) {
                float xv = xs[base + t];               // LDS broadcast
                v2f nt = w1 * g.xx + b2 * xv;          // (wr*gr + 2br*x, wi*gr + 2bi*x)
                g = w2 * g.yy + nt;                    // g' = w*g + 2b*x
                rs[t][lane] = g.x;                     // Re(g) contribution
            }
            __syncthreads();
            // transpose-reduce: lane -> (t = lane&31, half = lane>>5)
            const int tr = lane & 31;
            const int h = lane >> 5;
            float a0 = 0.0f, a1 = 0.0f;
#pragma unroll
            for (int k = 0; k < 32; k += 2) {
                a0 += rs[tr][h * 32 + k];
                a1 += rs[tr][h * 32 + k + 1];
            }
            float a = a0 + a1;
            a += __shfl_xor(a, 32);                    // combine halves
            if (lane < 32) yp[tile * 64 + base + lane] = a;  // coalesced 128B store
            __syncthreads();                           // protect rs (and xs at tile end)
        }
    }
}

extern "C" void kernel_launch(void* const* d_in, const int* in_sizes, int n_in,
                              void* d_out, int out_size, void* d_ws, size_t ws_size,
                              hipStream_t stream) {
    const float* x      = (const float*)d_in[0];
    const float* log_dt = (const float*)d_in[1];
    const float* a_real = (const float*)d_in[2];
    const float* a_imag = (const float*)d_in[3];
    const float* cv     = (const float*)d_in[4];
    float* y = (float*)d_out;
    float4* params = (float4*)d_ws;   // 256 KiB, recomputed every call (ws is re-poisoned)

    hipLaunchKernelGGL(s4d_params, dim3((NC * NS + 255) / 256), dim3(256), 0, stream,
                       log_dt, a_real, a_imag, cv, params);
    hipLaunchKernelGGL(s4d_scan, dim3(NB * NC), dim3(64), 0, stream,
                       x, params, y);
}